// Round 7
// baseline (332.998 us; speedup 1.0000x reference)
//
#include <hip/hip_runtime.h>
#include <cstdint>
#include <cstddef>

typedef short short8 __attribute__((ext_vector_type(8)));
typedef short short4v __attribute__((ext_vector_type(4)));
typedef float floatx4 __attribute__((ext_vector_type(4)));
typedef unsigned short ushort4v __attribute__((ext_vector_type(4)));

constexpr int B_ = 2, S_ = 2048, H_ = 1024, NH_ = 16, DH_ = 64;
constexpr int K_ = H_;        // 1024

__device__ __forceinline__ unsigned short f2bf(float f) {
  unsigned u = __float_as_uint(f);
  u += 0x7fffu + ((u >> 16) & 1u);   // RNE
  return (unsigned short)(u >> 16);
}

// pack two floats to bf16x2 (round-half-up; bias cancels in p/sum(p))
__device__ __forceinline__ unsigned pack2bf(float a, float b) {
  unsigned ua = (__float_as_uint(a) + 0x8000u) >> 16;
  unsigned ub = (__float_as_uint(b) + 0x8000u) & 0xffff0000u;
  return ua | ub;
}

// ---------------- fp32 -> bf16 conversion ----------------
__global__ __launch_bounds__(256) void cvt_bf16(const float* __restrict__ in,
                                                unsigned short* __restrict__ out, int n) {
  int i = (blockIdx.x * blockDim.x + threadIdx.x) * 4;
  if (i >= n) return;
  float4 v = *reinterpret_cast<const float4*>(in + i);
  ushort4v o;
  o.x = f2bf(v.x); o.y = f2bf(v.y); o.z = f2bf(v.z); o.w = f2bf(v.w);
  *reinterpret_cast<ushort4v*>(out + i) = o;
}

// ---------------- local mask -> bitmask (1 bit/key) ----------------
__global__ __launch_bounds__(256) void build_bitmask(const int* __restrict__ lm,
                                                     unsigned long long* __restrict__ bm) {
  int word = blockIdx.x * 4 + (threadIdx.x >> 6);
  int lane = threadIdx.x & 63;
  unsigned long long bits = __ballot(lm[(size_t)word * 64 + lane] != 0);
  if (lane == 0) bm[word] = bits;
}

// ---------------- exp(amask) table [B,S] ----------------
__global__ __launch_bounds__(256) void build_eam(const float* __restrict__ am,
                                                 float* __restrict__ ea) {
  int i = blockIdx.x * 256 + threadIdx.x;
  ea[i] = __expf(am[i]);
}

// ---------------- async global->LDS 16B ----------------
typedef __attribute__((address_space(1))) const void gvoid;
typedef __attribute__((address_space(3))) void lvoid;
__device__ __forceinline__ void async16(const unsigned short* gp, unsigned short* lp) {
  __builtin_amdgcn_global_load_lds((gvoid*)gp, (lvoid*)lp, 16, 0, 0);
}

// ---------------- QKV projection GEMM (unchanged, verified) ----------------
__global__ __launch_bounds__(256) void gemm_qkv(
    const unsigned short* __restrict__ A,
    const unsigned short* __restrict__ Wq, const unsigned short* __restrict__ Wk,
    const unsigned short* __restrict__ Wv,
    const float* __restrict__ bq, const float* __restrict__ bk, const float* __restrict__ bv,
    unsigned short* __restrict__ qo, unsigned short* __restrict__ ko,
    unsigned short* __restrict__ vo) {
  __shared__ alignas(16) unsigned short As[128 * 32];
  __shared__ alignas(16) unsigned short Bs[128 * 32];
  const int z = blockIdx.z;
  const unsigned short* W = (z == 0) ? Wq : (z == 1) ? Wk : Wv;
  const float* bias = (z == 0) ? bq : (z == 1) ? bk : bv;
  const float oscale = (z == 0) ? 0.125f : 1.0f;

  const int m0 = blockIdx.x * 128, n0 = blockIdx.y * 128;
  const int tid = threadIdx.x, lane = tid & 63, wvi = tid >> 6;
  const int wr = wvi >> 1, wc = wvi & 1, quad = lane >> 4, l16 = lane & 15;

  floatx4 zf = {0.f, 0.f, 0.f, 0.f};
  floatx4 acc[4][4];
  for (int i = 0; i < 4; i++)
    for (int j = 0; j < 4; j++) acc[i][j] = zf;

  for (int kk = 0; kk < K_; kk += 32) {
#pragma unroll
    for (int i = 0; i < 2; i++) {
      int cb = wvi * 128 + i * 64;   // wave-uniform chunk base (lds dest = base + lane*16B)
      int c = cb + lane;
      int row = c >> 2, kc = c & 3;
      async16(A + (size_t)(m0 + row) * K_ + kk + kc * 8, As + cb * 8);
      async16(W + (size_t)(n0 + row) * K_ + kk + kc * 8, Bs + cb * 8);
    }
    __syncthreads();
    short8 af[4], bfr[4];
#pragma unroll
    for (int mf = 0; mf < 4; mf++)
      af[mf] = *reinterpret_cast<const short8*>(&As[(wr * 64 + mf * 16 + l16) * 32 + quad * 8]);
#pragma unroll
    for (int nf = 0; nf < 4; nf++)
      bfr[nf] = *reinterpret_cast<const short8*>(&Bs[(wc * 64 + nf * 16 + l16) * 32 + quad * 8]);
#pragma unroll
    for (int mf = 0; mf < 4; mf++)
#pragma unroll
      for (int nf = 0; nf < 4; nf++)
        acc[mf][nf] = __builtin_amdgcn_mfma_f32_16x16x32_bf16(af[mf], bfr[nf], acc[mf][nf], 0, 0, 0);
    __syncthreads();
  }

  unsigned short* outp = (z == 0) ? qo : (z == 1) ? ko : vo;
#pragma unroll
  for (int mf = 0; mf < 4; mf++) {
    int mbase = m0 + wr * 64 + mf * 16 + quad * 4;
    int b = mbase >> 11, s = mbase & 2047;
#pragma unroll
    for (int nf = 0; nf < 4; nf++) {
      int n = n0 + wc * 64 + nf * 16 + l16;
      int h = n >> 6, d = n & 63;
      float bvv = bias[n];
      floatx4 c = acc[mf][nf];
      if (z < 2) {
#pragma unroll
        for (int r = 0; r < 4; r++) {
          float val = (c[r] + bvv) * oscale;
          outp[((size_t)(b * NH_ + h) * S_ + (s + r)) * DH_ + d] = f2bf(val);
        }
      } else {
        ushort4v p;
        p.x = f2bf(c[0] + bvv); p.y = f2bf(c[1] + bvv);
        p.z = f2bf(c[2] + bvv); p.w = f2bf(c[3] + bvv);
        *reinterpret_cast<ushort4v*>(&outp[((size_t)(b * NH_ + h) * DH_ + d) * S_ + s]) = p;
      }
    }
  }
}

// ------- dual-softmax flash attention: transposed scores + DMA-staged K/V -------
// Sᵀ = K·Qᵀ (swapped MFMA operands); exp(Sᵀ) packs in-lane into B-frags for
// Oᵀ = Vᵀ·P (K=16 MFMA). P never leaves registers.
// K/V tiles staged by global_load_lds (16B/lane DMA, no VGPR round-trip),
// double-buffered with ONE barrier per iter:
//   barrier -> issue async tile kt+1 into buf^1 -> compute kt from buf^0.
// The barrier's vmcnt drain hits loads issued a full iteration earlier.
// LDS layouts are FRAGMENT-ORDER (legal because global_load_lds allows
// arbitrary per-lane global addrs while LDS dest = base + lane*16B):
//   K: elem t*1024 + (c*16 + key15)*8 + e   (c = dh>>3)
//      -> QK b128 read at t*1024 (+512) + lane*8: perfectly coalesced, 0 conflicts
//   V: elem (d*4+t)*256 + x*4 + e, x = l16*4+quad, holding V[d*16+(x>>2)][t*16+(x&3)*4+e]
//      -> PV b64 read: 16 disjoint 2-bank windows * 4 dwords = minimum cycles, 0 conflicts
__global__ __launch_bounds__(256, 4) void attn_kernel(
    const unsigned short* __restrict__ q,   // [B,NH,S,DH] bf16, pre-scaled by 0.125
    const unsigned short* __restrict__ k,   // [B,NH,S,DH] bf16
    const unsigned short* __restrict__ vt,  // [B,NH,DH,S] bf16
    const float* __restrict__ eam,          // [B,S] = exp(amask)
    const unsigned long long* __restrict__ bm,  // [B,S,S/64] bitmask
    const float* __restrict__ gate,         // [B,NH,S]
    float* __restrict__ out) {              // [B,S,H]
  __shared__ alignas(16) unsigned short Ks[2][4096];
  __shared__ alignas(16) unsigned short Vs[2][4096];

  const int qt = blockIdx.x, h = blockIdx.y, b = blockIdx.z;
  const int tid = threadIdx.x, lane = tid & 63, wvi = tid >> 6;
  const int quad = lane >> 4, l16 = lane & 15;
  const int bh = b * NH_ + h;
  const int q0 = qt * 64 + wvi * 16;  // wave's 16 q-rows; this lane's q = q0+l16

  const unsigned short* qrow = q + ((size_t)bh * S_ + q0 + l16) * DH_;
  short8 qf0 = *reinterpret_cast<const short8*>(qrow + quad * 8);
  short8 qf1 = *reinterpret_cast<const short8*>(qrow + 32 + quad * 8);

  floatx4 zf = {0.f, 0.f, 0.f, 0.f};
  float psg = 0.f, psl = 0.f;
  floatx4 accg[4], accl[4];   // Oᵀ tiles: row d = dtile*16+quad*4+r, col q = l16
#pragma unroll
  for (int i = 0; i < 4; i++) { accg[i] = zf; accl[i] = zf; }

  const unsigned short* kp = k + (size_t)bh * S_ * DH_;
  const unsigned short* vp = vt + (size_t)bh * DH_ * S_;
  const float* eamb = eam + (size_t)b * S_;
  const unsigned long long* bmq = bm + ((size_t)b * S_ + q0 + l16) * (S_ / 64);

  // DMA source addresses (per lane). Wave wvi stages K sub-tile t=wvi and
  // V sub-tiles d=wvi; 4 async16 per wave per tile (K j=0,1; V j=0,1).
  //   K instr j, lane L: global K[key = k0 + wvi*16 + (L&15)][dh = j*32 + (L>>4)*8 ..+7]
  //                      -> LDS Ks[buf] + wvi*1024 + j*512 + L*8
  //   V instr j, lane L: global V[dh = wvi*16 + ((L&31)>>1)][key = k0 + (2j+(L>>5))*16 + (L&1)*8 ..+7]
  //                      -> LDS Vs[buf] + wvi*1024 + j*512 + L*8
  const unsigned short* kgl = kp + (wvi * 16 + l16) * DH_ + quad * 8;
  const unsigned short* vgl =
      vp + (size_t)(wvi * 16 + ((lane & 31) >> 1)) * S_ + (lane >> 5) * 16 + (lane & 1) * 8;
  unsigned short* klb[2] = {&Ks[0][wvi * 1024], &Ks[1][wvi * 1024]};
  unsigned short* vlb[2] = {&Vs[0][wvi * 1024], &Vs[1][wvi * 1024]};

  // prologue: stage tile 0 into buffer 0
  async16(kgl, klb[0]);
  async16(kgl + 32, klb[0] + 512);
  async16(vgl, vlb[0]);
  async16(vgl + 32, vlb[0] + 512);

  const int vro = l16 * 16 + quad * 4;  // PV read sub-offset (elems)

  for (int kt = 0; kt < S_ / 64; kt++) {
    __syncthreads();  // tile kt's DMA drained (vmcnt) and visible to all waves
    // ---- issue async stage of tile kt+1 into the other buffer ----
    if (kt < S_ / 64 - 1) {
      const int k0n = (kt + 1) * 64;
      const int bn = (kt + 1) & 1;
      const unsigned short* kg = kgl + k0n * DH_;
      const unsigned short* vg = vgl + k0n;
      async16(kg, klb[bn]);
      async16(kg + 32, klb[bn] + 512);
      async16(vg, vlb[bn]);
      async16(vg + 32, vlb[bn] + 512);
    }
    const int k0 = kt * 64;
    // ---- per-lane mask bits + eam (independent loads, issued early) ----
    unsigned long long w = bmq[kt];
    float4 ea[4];
#pragma unroll
    for (int t = 0; t < 4; t++)
      ea[t] = *reinterpret_cast<const float4*>(eamb + k0 + t * 16 + quad * 4);

    const unsigned short* Kc = Ks[kt & 1];
    const unsigned short* Vc = Vs[kt & 1];
    // ---- QKᵀ from LDS (coalesced b128 reads) ----
    floatx4 scT[4];
#pragma unroll
    for (int t = 0; t < 4; t++) {
      const unsigned short* kr = Kc + t * 1024 + lane * 8;
      short8 kf0 = *reinterpret_cast<const short8*>(kr);
      short8 kf1 = *reinterpret_cast<const short8*>(kr + 512);
      scT[t] = __builtin_amdgcn_mfma_f32_16x16x32_bf16(kf0, qf0, zf, 0, 0, 0);
      scT[t] = __builtin_amdgcn_mfma_f32_16x16x32_bf16(kf1, qf1, scT[t], 0, 0, 0);
    }
    // ---- shared-exp dual softmax; pack P into B-frags in-lane ----
    int pgf[4][2], plf[4][2];
#pragma unroll
    for (int t = 0; t < 4; t++) {
      unsigned m4 = (unsigned)(w >> (t * 16 + quad * 4)) & 0xFu;
      float e0 = __expf(scT[t][0]), e1 = __expf(scT[t][1]);
      float e2 = __expf(scT[t][2]), e3 = __expf(scT[t][3]);
      float g0 = e0 * ea[t].x, g1 = e1 * ea[t].y, g2 = e2 * ea[t].z, g3 = e3 * ea[t].w;
      psg += (g0 + g1) + (g2 + g3);
      float l0 = (m4 & 1u) ? e0 : 0.f;
      float l1 = (m4 & 2u) ? e1 : 0.f;
      float l2 = (m4 & 4u) ? e2 : 0.f;
      float l3 = (m4 & 8u) ? e3 : 0.f;
      psl += (l0 + l1) + (l2 + l3);
      pgf[t][0] = pack2bf(g0, g1); pgf[t][1] = pack2bf(g2, g3);
      plf[t][0] = pack2bf(l0, l1); plf[t][1] = pack2bf(l2, l3);
    }
    // ---- PV from LDS Vᵀ: Oᵀ += Vᵀ·P (K=16 MFMAs, conflict-free b64 reads) ----
#pragma unroll
    for (int d = 0; d < 4; d++) {
#pragma unroll
      for (int t = 0; t < 4; t++) {
        short4v vf = *reinterpret_cast<const short4v*>(Vc + (d * 4 + t) * 256 + vro);
        short4v pg = *reinterpret_cast<const short4v*>(&pgf[t][0]);
        short4v pl = *reinterpret_cast<const short4v*>(&plf[t][0]);
        accg[d] = __builtin_amdgcn_mfma_f32_16x16x16bf16_1k(vf, pg, accg[d], 0, 0, 0);
        accl[d] = __builtin_amdgcn_mfma_f32_16x16x16bf16_1k(vf, pl, accl[d], 0, 0, 0);
      }
    }
  }

  // ---- epilogue: quad-reduce denominators, gate-combine, float4 stores ----
  float lgf = psg;
  lgf += __shfl_xor(lgf, 16, 64);
  lgf += __shfl_xor(lgf, 32, 64);
  float llf = psl;
  llf += __shfl_xor(llf, 16, 64);
  llf += __shfl_xor(llf, 32, 64);
  const int s = q0 + l16;
  const float g = gate[(size_t)bh * S_ + s];
  const float cg = (1.f - g) / lgf, cl = g / llf;
  float* orow = out + ((size_t)b * S_ + s) * H_ + h * DH_ + quad * 4;
#pragma unroll
  for (int d = 0; d < 4; d++) {
    float4 o;
    o.x = cl * accl[d][0] + cg * accg[d][0];
    o.y = cl * accl[d][1] + cg * accg[d][1];
    o.z = cl * accl[d][2] + cg * accg[d][2];
    o.w = cl * accl[d][3] + cg * accg[d][3];
    *reinterpret_cast<float4*>(orow + d * 16) = o;
  }
}

extern "C" void kernel_launch(void* const* d_in, const int* in_sizes, int n_in,
                              void* d_out, int out_size, void* d_ws, size_t ws_size,
                              hipStream_t stream) {
  (void)in_sizes; (void)n_in; (void)out_size; (void)ws_size;
  const float* hs = (const float*)d_in[0];
  const float* am = (const float*)d_in[1];
  const int* lm = (const int*)d_in[2];
  const float* gate = (const float*)d_in[3];
  const float* Wq = (const float*)d_in[4];
  const float* bq = (const float*)d_in[5];
  const float* Wk = (const float*)d_in[6];
  const float* bk = (const float*)d_in[7];
  const float* Wv = (const float*)d_in[8];
  const float* bv = (const float*)d_in[9];
  float* out = (float*)d_out;

  unsigned short* ws = (unsigned short*)d_ws;
  unsigned short* hbf = ws;                  // 4,194,304 elems
  unsigned short* wqb = hbf + 4194304;       // 1,048,576
  unsigned short* wkb = wqb + 1048576;
  unsigned short* wvb = wkb + 1048576;
  unsigned short* qb = wvb + 1048576;        // 4,194,304
  unsigned short* kb = qb + 4194304;
  unsigned short* vtb = kb + 4194304;
  unsigned long long* bmp = (unsigned long long*)(vtb + 4194304);  // 1 MB
  float* eamp = (float*)(bmp + 131072);      // 4096 floats

  cvt_bf16<<<4096, 256, 0, stream>>>(hs, hbf, 4194304);
  cvt_bf16<<<1024, 256, 0, stream>>>(Wq, wqb, 1048576);
  cvt_bf16<<<1024, 256, 0, stream>>>(Wk, wkb, 1048576);
  cvt_bf16<<<1024, 256, 0, stream>>>(Wv, wvb, 1048576);
  build_bitmask<<<32768, 256, 0, stream>>>(lm, bmp);
  build_eam<<<16, 256, 0, stream>>>(am, eamp);
  gemm_qkv<<<dim3(32, 8, 3), 256, 0, stream>>>(hbf, wqb, wkb, wvb, bq, bk, bv, qb, kb, vtb);
  attn_kernel<<<dim3(32, 16, 2), 256, 0, stream>>>(qb, kb, vtb, eamp, bmp, gate, out);
}

// Round 8
// 285.407 us; speedup vs baseline: 1.1667x; 1.1667x over previous
//
#include <hip/hip_runtime.h>
#include <cstdint>
#include <cstddef>

typedef short short8 __attribute__((ext_vector_type(8)));
typedef short short4v __attribute__((ext_vector_type(4)));
typedef float floatx4 __attribute__((ext_vector_type(4)));
typedef unsigned short ushort4v __attribute__((ext_vector_type(4)));

constexpr int B_ = 2, S_ = 2048, H_ = 1024, NH_ = 16, DH_ = 64;
constexpr int K_ = H_;        // 1024

__device__ __forceinline__ unsigned short f2bf(float f) {
  unsigned u = __float_as_uint(f);
  u += 0x7fffu + ((u >> 16) & 1u);   // RNE
  return (unsigned short)(u >> 16);
}

// pack two floats to bf16x2 (round-half-up; bias cancels in p/sum(p))
__device__ __forceinline__ unsigned pack2bf(float a, float b) {
  unsigned ua = (__float_as_uint(a) + 0x8000u) >> 16;
  unsigned ub = (__float_as_uint(b) + 0x8000u) & 0xffff0000u;
  return ua | ub;
}

// ---------------- fp32 -> bf16 conversion ----------------
__global__ __launch_bounds__(256) void cvt_bf16(const float* __restrict__ in,
                                                unsigned short* __restrict__ out, int n) {
  int i = (blockIdx.x * blockDim.x + threadIdx.x) * 4;
  if (i >= n) return;
  float4 v = *reinterpret_cast<const float4*>(in + i);
  ushort4v o;
  o.x = f2bf(v.x); o.y = f2bf(v.y); o.z = f2bf(v.z); o.w = f2bf(v.w);
  *reinterpret_cast<ushort4v*>(out + i) = o;
}

// ---------------- local mask -> bitmask (1 bit/key) ----------------
__global__ __launch_bounds__(256) void build_bitmask(const int* __restrict__ lm,
                                                     unsigned long long* __restrict__ bm) {
  int word = blockIdx.x * 4 + (threadIdx.x >> 6);
  int lane = threadIdx.x & 63;
  unsigned long long bits = __ballot(lm[(size_t)word * 64 + lane] != 0);
  if (lane == 0) bm[word] = bits;
}

// ---------------- exp(amask) table [B,S] ----------------
__global__ __launch_bounds__(256) void build_eam(const float* __restrict__ am,
                                                 float* __restrict__ ea) {
  int i = blockIdx.x * 256 + threadIdx.x;
  ea[i] = __expf(am[i]);
}

// ---------------- async global->LDS 16B ----------------
typedef __attribute__((address_space(1))) const void gvoid;
typedef __attribute__((address_space(3))) void lvoid;
__device__ __forceinline__ void async16(const unsigned short* gp, unsigned short* lp) {
  __builtin_amdgcn_global_load_lds((gvoid*)gp, (lvoid*)lp, 16, 0, 0);
}

// ---------------- QKV projection GEMM ----------------
// z=0 -> q (scaled 0.125) [B,NH,S,DH].
// z=1 -> K in FRAGMENT-TILE order: per (bh, kt=key>>6) 4096-elem tile,
//        idx = ((key>>4)&3)*1024 + (dh>>5)*512 + ((dh>>3)&3)*128 + (key&15)*8 + (dh&7)
// z=2 -> V in FRAGMENT-TILE order: per (bh, kt) tile,
//        idx = (dh>>4)*1024 + ((key>>4)&3)*256 + ((key>>2)&3)*64 + (dh&15)*4 + (key&3)
// These make the attention staging loads flat/coalesced and every attn ds_read
// lane-order contiguous (zero bank conflicts).
__global__ __launch_bounds__(256) void gemm_qkv(
    const unsigned short* __restrict__ A,
    const unsigned short* __restrict__ Wq, const unsigned short* __restrict__ Wk,
    const unsigned short* __restrict__ Wv,
    const float* __restrict__ bq, const float* __restrict__ bk, const float* __restrict__ bv,
    unsigned short* __restrict__ qo, unsigned short* __restrict__ ko,
    unsigned short* __restrict__ vo) {
  __shared__ alignas(16) unsigned short As[128 * 32];
  __shared__ alignas(16) unsigned short Bs[128 * 32];
  const int z = blockIdx.z;
  const unsigned short* W = (z == 0) ? Wq : (z == 1) ? Wk : Wv;
  const float* bias = (z == 0) ? bq : (z == 1) ? bk : bv;

  const int m0 = blockIdx.x * 128, n0 = blockIdx.y * 128;
  const int tid = threadIdx.x, lane = tid & 63, wvi = tid >> 6;
  const int wr = wvi >> 1, wc = wvi & 1, quad = lane >> 4, l16 = lane & 15;

  floatx4 zf = {0.f, 0.f, 0.f, 0.f};
  floatx4 acc[4][4];
  for (int i = 0; i < 4; i++)
    for (int j = 0; j < 4; j++) acc[i][j] = zf;

  for (int kk = 0; kk < K_; kk += 32) {
#pragma unroll
    for (int i = 0; i < 2; i++) {
      int cb = wvi * 128 + i * 64;   // wave-uniform chunk base (lds dest = base + lane*16B)
      int c = cb + lane;
      int row = c >> 2, kc = c & 3;
      async16(A + (size_t)(m0 + row) * K_ + kk + kc * 8, As + cb * 8);
      async16(W + (size_t)(n0 + row) * K_ + kk + kc * 8, Bs + cb * 8);
    }
    __syncthreads();
    short8 af[4], bfr[4];
#pragma unroll
    for (int mf = 0; mf < 4; mf++)
      af[mf] = *reinterpret_cast<const short8*>(&As[(wr * 64 + mf * 16 + l16) * 32 + quad * 8]);
#pragma unroll
    for (int nf = 0; nf < 4; nf++)
      bfr[nf] = *reinterpret_cast<const short8*>(&Bs[(wc * 64 + nf * 16 + l16) * 32 + quad * 8]);
#pragma unroll
    for (int mf = 0; mf < 4; mf++)
#pragma unroll
      for (int nf = 0; nf < 4; nf++)
        acc[mf][nf] = __builtin_amdgcn_mfma_f32_16x16x32_bf16(af[mf], bfr[nf], acc[mf][nf], 0, 0, 0);
    __syncthreads();
  }

  unsigned short* outp = (z == 0) ? qo : (z == 1) ? ko : vo;
#pragma unroll
  for (int mf = 0; mf < 4; mf++) {
    int mbase = m0 + wr * 64 + mf * 16 + quad * 4;  // key/seq base (mult of 4)
    int b = mbase >> 11, s0 = mbase & 2047;
#pragma unroll
    for (int nf = 0; nf < 4; nf++) {
      int n = n0 + wc * 64 + nf * 16 + l16;
      int h = n >> 6, d = n & 63;
      int bh = b * NH_ + h;
      float bvv = bias[n];
      floatx4 c = acc[mf][nf];
      if (z == 0) {
#pragma unroll
        for (int r = 0; r < 4; r++) {
          float val = (c[r] + bvv) * 0.125f;
          outp[((size_t)bh * S_ + (s0 + r)) * DH_ + d] = f2bf(val);
        }
      } else if (z == 1) {
        size_t base = (size_t)bh * 131072 + (s0 >> 6) * 4096 + ((s0 >> 4) & 3) * 1024 +
                      (d >> 5) * 512 + ((d >> 3) & 3) * 128 + (d & 7);
#pragma unroll
        for (int r = 0; r < 4; r++)
          outp[base + ((s0 & 15) + r) * 8] = f2bf(c[r] + bvv);
      } else {
        // keys s0..s0+3 at dh=d -> j' = 0..3 contiguous (8B write)
        size_t base = (size_t)bh * 131072 + (s0 >> 6) * 4096 + (d >> 4) * 1024 +
                      ((s0 >> 4) & 3) * 256 + ((s0 >> 2) & 3) * 64 + (d & 15) * 4;
        ushort4v p;
        p.x = f2bf(c[0] + bvv); p.y = f2bf(c[1] + bvv);
        p.z = f2bf(c[2] + bvv); p.w = f2bf(c[3] + bvv);
        *reinterpret_cast<ushort4v*>(&outp[base]) = p;
      }
    }
  }
}

// ------- dual-softmax flash attention: transposed scores, VGPR-staged K/V -------
// Sᵀ = K·Qᵀ (swapped MFMA operands); exp(Sᵀ) packs in-lane into B-frags for
// Oᵀ = Vᵀ·P (K=16 MFMA). P never leaves registers.
// K/V are pre-permuted in GLOBAL memory (gemm epilogue) into fragment-tile
// order, so: staging global loads are flat tid*32B (perfect coalescing), the
// LDS copy is identity, and all in-loop ds_reads are lane-order contiguous:
//   QK b128: byte = lane*16 (8 lanes/cyc -> 128B contiguous, 0 conflicts)
//   PV b64:  byte = lane*8 (16 lanes/cyc -> 128B contiguous, 0 conflicts)
// (r7 lesson: conflicts are determined by LANE-ORDER address contiguity within
//  8/16-lane groups; l16-major addressing was 4-way conflicted = 98K cyc/CU.)
// Structure: r6's proven VGPR double-buffer (regs prefetch kt+1 during compute).
// XCD swizzle: blocks of head h land on XCD h&7 -> per-XCD L2 working set
// = 2 heads x 2 batches x 512KB = 2MB < 4MB.
__global__ __launch_bounds__(256, 4) void attn_kernel(
    const unsigned short* __restrict__ q,   // [B,NH,S,DH] bf16, pre-scaled by 0.125
    const unsigned short* __restrict__ kperm,  // fragment-tile K
    const unsigned short* __restrict__ vperm,  // fragment-tile V
    const float* __restrict__ eam,          // [B,S] = exp(amask)
    const unsigned long long* __restrict__ bm,  // [B,S,S/64] bitmask
    const float* __restrict__ gate,         // [B,NH,S]
    float* __restrict__ out) {              // [B,S,H]
  __shared__ alignas(16) unsigned short Ks[2][4096];
  __shared__ alignas(16) unsigned short Vs[2][4096];

  const int flat = blockIdx.x;
  const int h = (flat & 7) + 8 * ((flat >> 3) & 1);
  const int b = (flat >> 4) & 1;
  const int qt = flat >> 5;
  const int tid = threadIdx.x, lane = tid & 63, wvi = tid >> 6;
  const int quad = lane >> 4, l16 = lane & 15;
  const int bh = b * NH_ + h;
  const int q0 = qt * 64 + wvi * 16;  // wave's 16 q-rows; this lane's q = q0+l16

  const unsigned short* qrow = q + ((size_t)bh * S_ + q0 + l16) * DH_;
  short8 qf0 = *reinterpret_cast<const short8*>(qrow + quad * 8);
  short8 qf1 = *reinterpret_cast<const short8*>(qrow + 32 + quad * 8);

  floatx4 zf = {0.f, 0.f, 0.f, 0.f};
  float psg = 0.f, psl = 0.f;
  floatx4 accg[4], accl[4];   // Oᵀ tiles: row d = dtile*16+quad*4+r, col q = l16
#pragma unroll
  for (int i = 0; i < 4; i++) { accg[i] = zf; accl[i] = zf; }

  const unsigned short* kp = kperm + (size_t)bh * 131072;
  const unsigned short* vp = vperm + (size_t)bh * 131072;
  const float* eamb = eam + (size_t)b * S_;
  const unsigned long long* bmq = bm + ((size_t)b * S_ + q0 + l16) * (S_ / 64);

  // flat staging: thread tid copies elems [tid*16, tid*16+16) of each 4096-elem tile
  const unsigned short* kg0 = kp + tid * 16;
  const unsigned short* vg0 = vp + tid * 16;
  const int so = tid * 16;

  // prologue: stage tile 0 into buffer 0
  uint4 pk0 = *reinterpret_cast<const uint4*>(kg0);
  uint4 pk1 = *reinterpret_cast<const uint4*>(kg0 + 8);
  uint4 pv0 = *reinterpret_cast<const uint4*>(vg0);
  uint4 pv1 = *reinterpret_cast<const uint4*>(vg0 + 8);
  *reinterpret_cast<uint4*>(&Ks[0][so]) = pk0;
  *reinterpret_cast<uint4*>(&Ks[0][so + 8]) = pk1;
  *reinterpret_cast<uint4*>(&Vs[0][so]) = pv0;
  *reinterpret_cast<uint4*>(&Vs[0][so + 8]) = pv1;

  for (int kt = 0; kt < S_ / 64; kt++) {
    __syncthreads();  // buf[kt&1] staged and visible
    // ---- prefetch tile kt+1 into regs (wraps; no dependent use this iter) ----
    {
      const int tb = ((kt + 1) & 31) * 4096;
      pk0 = *reinterpret_cast<const uint4*>(kg0 + tb);
      pk1 = *reinterpret_cast<const uint4*>(kg0 + tb + 8);
      pv0 = *reinterpret_cast<const uint4*>(vg0 + tb);
      pv1 = *reinterpret_cast<const uint4*>(vg0 + tb + 8);
    }
    const int k0 = kt * 64;
    // ---- per-lane mask bits + eam (independent loads, issued early) ----
    unsigned long long w = bmq[kt];
    float4 ea[4];
#pragma unroll
    for (int t = 0; t < 4; t++)
      ea[t] = *reinterpret_cast<const float4*>(eamb + k0 + t * 16 + quad * 4);

    const unsigned short* Kc = Ks[kt & 1];
    const unsigned short* Vc = Vs[kt & 1];
    // ---- QKᵀ from LDS (lane-order contiguous b128 reads) ----
    floatx4 scT[4];
#pragma unroll
    for (int t = 0; t < 4; t++) {
      const unsigned short* kr = Kc + t * 1024 + lane * 8;
      short8 kf0 = *reinterpret_cast<const short8*>(kr);
      short8 kf1 = *reinterpret_cast<const short8*>(kr + 512);
      scT[t] = __builtin_amdgcn_mfma_f32_16x16x32_bf16(kf0, qf0, zf, 0, 0, 0);
      scT[t] = __builtin_amdgcn_mfma_f32_16x16x32_bf16(kf1, qf1, scT[t], 0, 0, 0);
    }
    // ---- shared-exp dual softmax; pack P into B-frags in-lane ----
    int pgf[4][2], plf[4][2];
#pragma unroll
    for (int t = 0; t < 4; t++) {
      unsigned m4 = (unsigned)(w >> (t * 16 + quad * 4)) & 0xFu;
      float e0 = __expf(scT[t][0]), e1 = __expf(scT[t][1]);
      float e2 = __expf(scT[t][2]), e3 = __expf(scT[t][3]);
      float g0 = e0 * ea[t].x, g1 = e1 * ea[t].y, g2 = e2 * ea[t].z, g3 = e3 * ea[t].w;
      psg += (g0 + g1) + (g2 + g3);
      float l0 = (m4 & 1u) ? e0 : 0.f;
      float l1 = (m4 & 2u) ? e1 : 0.f;
      float l2 = (m4 & 4u) ? e2 : 0.f;
      float l3 = (m4 & 8u) ? e3 : 0.f;
      psl += (l0 + l1) + (l2 + l3);
      pgf[t][0] = pack2bf(g0, g1); pgf[t][1] = pack2bf(g2, g3);
      plf[t][0] = pack2bf(l0, l1); plf[t][1] = pack2bf(l2, l3);
    }
    // ---- PV from LDS: Oᵀ += Vᵀ·P (lane-order contiguous b64 reads) ----
#pragma unroll
    for (int d = 0; d < 4; d++) {
#pragma unroll
      for (int t = 0; t < 4; t++) {
        short4v vf = *reinterpret_cast<const short4v*>(Vc + d * 1024 + t * 256 + lane * 4);
        short4v pg = *reinterpret_cast<const short4v*>(&pgf[t][0]);
        short4v pl = *reinterpret_cast<const short4v*>(&plf[t][0]);
        accg[d] = __builtin_amdgcn_mfma_f32_16x16x16bf16_1k(vf, pg, accg[d], 0, 0, 0);
        accl[d] = __builtin_amdgcn_mfma_f32_16x16x16bf16_1k(vf, pl, accl[d], 0, 0, 0);
      }
    }
    __syncthreads();  // all waves done reading buf[(kt+1)&1]
    // ---- stage prefetched tile kt+1 (lane-order contiguous b128 writes) ----
    {
      const int bn = (kt + 1) & 1;
      *reinterpret_cast<uint4*>(&Ks[bn][so]) = pk0;
      *reinterpret_cast<uint4*>(&Ks[bn][so + 8]) = pk1;
      *reinterpret_cast<uint4*>(&Vs[bn][so]) = pv0;
      *reinterpret_cast<uint4*>(&Vs[bn][so + 8]) = pv1;
    }
  }

  // ---- epilogue: quad-reduce denominators, gate-combine, float4 stores ----
  float lgf = psg;
  lgf += __shfl_xor(lgf, 16, 64);
  lgf += __shfl_xor(lgf, 32, 64);
  float llf = psl;
  llf += __shfl_xor(llf, 16, 64);
  llf += __shfl_xor(llf, 32, 64);
  const int s = q0 + l16;
  const float g = gate[(size_t)bh * S_ + s];
  const float cg = (1.f - g) / lgf, cl = g / llf;
  float* orow = out + ((size_t)b * S_ + s) * H_ + h * DH_ + quad * 4;
#pragma unroll
  for (int d = 0; d < 4; d++) {
    float4 o;
    o.x = cl * accl[d][0] + cg * accg[d][0];
    o.y = cl * accl[d][1] + cg * accg[d][1];
    o.z = cl * accl[d][2] + cg * accg[d][2];
    o.w = cl * accl[d][3] + cg * accg[d][3];
    *reinterpret_cast<float4*>(orow + d * 16) = o;
  }
}

extern "C" void kernel_launch(void* const* d_in, const int* in_sizes, int n_in,
                              void* d_out, int out_size, void* d_ws, size_t ws_size,
                              hipStream_t stream) {
  (void)in_sizes; (void)n_in; (void)out_size; (void)ws_size;
  const float* hs = (const float*)d_in[0];
  const float* am = (const float*)d_in[1];
  const int* lm = (const int*)d_in[2];
  const float* gate = (const float*)d_in[3];
  const float* Wq = (const float*)d_in[4];
  const float* bq = (const float*)d_in[5];
  const float* Wk = (const float*)d_in[6];
  const float* bk = (const float*)d_in[7];
  const float* Wv = (const float*)d_in[8];
  const float* bv = (const float*)d_in[9];
  float* out = (float*)d_out;

  unsigned short* ws = (unsigned short*)d_ws;
  unsigned short* hbf = ws;                  // 4,194,304 elems
  unsigned short* wqb = hbf + 4194304;       // 1,048,576
  unsigned short* wkb = wqb + 1048576;
  unsigned short* wvb = wkb + 1048576;
  unsigned short* qb = wvb + 1048576;        // 4,194,304
  unsigned short* kb = qb + 4194304;
  unsigned short* vtb = kb + 4194304;
  unsigned long long* bmp = (unsigned long long*)(vtb + 4194304);  // 1 MB
  float* eamp = (float*)(bmp + 131072);      // 4096 floats

  cvt_bf16<<<4096, 256, 0, stream>>>(hs, hbf, 4194304);
  cvt_bf16<<<1024, 256, 0, stream>>>(Wq, wqb, 1048576);
  cvt_bf16<<<1024, 256, 0, stream>>>(Wk, wkb, 1048576);
  cvt_bf16<<<1024, 256, 0, stream>>>(Wv, wvb, 1048576);
  build_bitmask<<<32768, 256, 0, stream>>>(lm, bmp);
  build_eam<<<16, 256, 0, stream>>>(am, eamp);
  gemm_qkv<<<dim3(32, 8, 3), 256, 0, stream>>>(hbf, wqb, wkb, wvb, bq, bk, bv, qb, kb, vtb);
  attn_kernel<<<dim3(1024), 256, 0, stream>>>(qb, kb, vtb, eamp, bmp, gate, out);
}

// Round 9
// 279.828 us; speedup vs baseline: 1.1900x; 1.0199x over previous
//
#include <hip/hip_runtime.h>
#include <cstdint>
#include <cstddef>

typedef short short8 __attribute__((ext_vector_type(8)));
typedef short short4v __attribute__((ext_vector_type(4)));
typedef float floatx4 __attribute__((ext_vector_type(4)));
typedef unsigned short ushort4v __attribute__((ext_vector_type(4)));

constexpr int B_ = 2, S_ = 2048, H_ = 1024, NH_ = 16, DH_ = 64;
constexpr int K_ = H_;        // 1024

__device__ __forceinline__ unsigned short f2bf(float f) {
  unsigned u = __float_as_uint(f);
  u += 0x7fffu + ((u >> 16) & 1u);   // RNE
  return (unsigned short)(u >> 16);
}

// pack two floats to bf16x2 (round-half-up; bias cancels in p/sum(p))
__device__ __forceinline__ unsigned pack2bf(float a, float b) {
  unsigned ua = (__float_as_uint(a) + 0x8000u) >> 16;
  unsigned ub = (__float_as_uint(b) + 0x8000u) & 0xffff0000u;
  return ua | ub;
}

// ---------------- fp32 -> bf16 conversion ----------------
__global__ __launch_bounds__(256) void cvt_bf16(const float* __restrict__ in,
                                                unsigned short* __restrict__ out, int n) {
  int i = (blockIdx.x * blockDim.x + threadIdx.x) * 4;
  if (i >= n) return;
  float4 v = *reinterpret_cast<const float4*>(in + i);
  ushort4v o;
  o.x = f2bf(v.x); o.y = f2bf(v.y); o.z = f2bf(v.z); o.w = f2bf(v.w);
  *reinterpret_cast<ushort4v*>(out + i) = o;
}

// ---------------- local mask -> bitmask (1 bit/key) ----------------
__global__ __launch_bounds__(256) void build_bitmask(const int* __restrict__ lm,
                                                     unsigned long long* __restrict__ bm) {
  int word = blockIdx.x * 4 + (threadIdx.x >> 6);
  int lane = threadIdx.x & 63;
  unsigned long long bits = __ballot(lm[(size_t)word * 64 + lane] != 0);
  if (lane == 0) bm[word] = bits;
}

// ---------------- exp(amask) table [B,S] ----------------
__global__ __launch_bounds__(256) void build_eam(const float* __restrict__ am,
                                                 float* __restrict__ ea) {
  int i = blockIdx.x * 256 + threadIdx.x;
  ea[i] = __expf(am[i]);
}

// ---------------- async global->LDS 16B ----------------
typedef __attribute__((address_space(1))) const void gvoid;
typedef __attribute__((address_space(3))) void lvoid;
__device__ __forceinline__ void async16(const unsigned short* gp, unsigned short* lp) {
  __builtin_amdgcn_global_load_lds((gvoid*)gp, (lvoid*)lp, 16, 0, 0);
}

// ---------------- QKV projection GEMM ----------------
// z=0 -> q scaled by 0.125*log2(e) [B,NH,S,DH]  (softmax uses exp2 directly)
// z=1 -> K in FRAGMENT-TILE order: per (bh, kt=key>>6) 4096-elem tile,
//        idx = ((key>>4)&3)*1024 + (dh>>5)*512 + ((dh>>3)&3)*128 + (key&15)*8 + (dh&7)
// z=2 -> V in FRAGMENT-TILE order: per (bh, kt) tile,
//        idx = (dh>>4)*1024 + ((key>>4)&3)*256 + ((key>>2)&3)*64 + (dh&15)*4 + (key&3)
__global__ __launch_bounds__(256) void gemm_qkv(
    const unsigned short* __restrict__ A,
    const unsigned short* __restrict__ Wq, const unsigned short* __restrict__ Wk,
    const unsigned short* __restrict__ Wv,
    const float* __restrict__ bq, const float* __restrict__ bk, const float* __restrict__ bv,
    unsigned short* __restrict__ qo, unsigned short* __restrict__ ko,
    unsigned short* __restrict__ vo) {
  __shared__ alignas(16) unsigned short As[128 * 32];
  __shared__ alignas(16) unsigned short Bs[128 * 32];
  const int z = blockIdx.z;
  const unsigned short* W = (z == 0) ? Wq : (z == 1) ? Wk : Wv;
  const float* bias = (z == 0) ? bq : (z == 1) ? bk : bv;

  const int m0 = blockIdx.x * 128, n0 = blockIdx.y * 128;
  const int tid = threadIdx.x, lane = tid & 63, wvi = tid >> 6;
  const int wr = wvi >> 1, wc = wvi & 1, quad = lane >> 4, l16 = lane & 15;

  floatx4 zf = {0.f, 0.f, 0.f, 0.f};
  floatx4 acc[4][4];
  for (int i = 0; i < 4; i++)
    for (int j = 0; j < 4; j++) acc[i][j] = zf;

  for (int kk = 0; kk < K_; kk += 32) {
#pragma unroll
    for (int i = 0; i < 2; i++) {
      int cb = wvi * 128 + i * 64;   // wave-uniform chunk base (lds dest = base + lane*16B)
      int c = cb + lane;
      int row = c >> 2, kc = c & 3;
      async16(A + (size_t)(m0 + row) * K_ + kk + kc * 8, As + cb * 8);
      async16(W + (size_t)(n0 + row) * K_ + kk + kc * 8, Bs + cb * 8);
    }
    __syncthreads();
    short8 af[4], bfr[4];
#pragma unroll
    for (int mf = 0; mf < 4; mf++)
      af[mf] = *reinterpret_cast<const short8*>(&As[(wr * 64 + mf * 16 + l16) * 32 + quad * 8]);
#pragma unroll
    for (int nf = 0; nf < 4; nf++)
      bfr[nf] = *reinterpret_cast<const short8*>(&Bs[(wc * 64 + nf * 16 + l16) * 32 + quad * 8]);
#pragma unroll
    for (int mf = 0; mf < 4; mf++)
#pragma unroll
      for (int nf = 0; nf < 4; nf++)
        acc[mf][nf] = __builtin_amdgcn_mfma_f32_16x16x32_bf16(af[mf], bfr[nf], acc[mf][nf], 0, 0, 0);
    __syncthreads();
  }

  unsigned short* outp = (z == 0) ? qo : (z == 1) ? ko : vo;
#pragma unroll
  for (int mf = 0; mf < 4; mf++) {
    int mbase = m0 + wr * 64 + mf * 16 + quad * 4;  // key/seq base (mult of 4)
    int b = mbase >> 11, s0 = mbase & 2047;
#pragma unroll
    for (int nf = 0; nf < 4; nf++) {
      int n = n0 + wc * 64 + nf * 16 + l16;
      int h = n >> 6, d = n & 63;
      int bh = b * NH_ + h;
      float bvv = bias[n];
      floatx4 c = acc[mf][nf];
      if (z == 0) {
#pragma unroll
        for (int r = 0; r < 4; r++) {
          float val = (c[r] + bvv) * 0.18033688011112042f;  // 0.125 * log2(e)
          outp[((size_t)bh * S_ + (s0 + r)) * DH_ + d] = f2bf(val);
        }
      } else if (z == 1) {
        size_t base = (size_t)bh * 131072 + (s0 >> 6) * 4096 + ((s0 >> 4) & 3) * 1024 +
                      (d >> 5) * 512 + ((d >> 3) & 3) * 128 + (d & 7);
#pragma unroll
        for (int r = 0; r < 4; r++)
          outp[base + ((s0 & 15) + r) * 8] = f2bf(c[r] + bvv);
      } else {
        size_t base = (size_t)bh * 131072 + (s0 >> 6) * 4096 + (d >> 4) * 1024 +
                      ((s0 >> 4) & 3) * 256 + ((s0 >> 2) & 3) * 64 + (d & 15) * 4;
        ushort4v p;
        p.x = f2bf(c[0] + bvv); p.y = f2bf(c[1] + bvv);
        p.z = f2bf(c[2] + bvv); p.w = f2bf(c[3] + bvv);
        *reinterpret_cast<ushort4v*>(&outp[base]) = p;
      }
    }
  }
}

// ------- dual-softmax flash attention: transposed scores, VGPR-staged K/V -------
// Sᵀ = K·Qᵀ (swapped MFMA operands); exp2(Sᵀ) packs in-lane into B-frags for
// Oᵀ = Vᵀ·P (K=16 MFMA). P never leaves registers. q pre-scaled by log2e/8 so
// softmax is raw v_exp_f32 (no per-element multiply).
// Single barrier per iter: barrier -> ds_write tile kt+1 (regs from last iter)
// -> global prefetch tile kt+2 -> compute kt. Buffer written = the one whose
// reads completed before this barrier (2-buffer invariant audited).
// All LDS ops lane-order contiguous (r7 lesson): staging writes are thread-
// contiguous 16B chunks (elems [tid*8,+8) and [2048+tid*8,+8)), QK b128 reads
// at lane*16B, PV b64 reads at lane*8B -> zero bank conflicts.
// XCD swizzle: head h -> XCD h&7; per-XCD L2 working set ~2MB < 4MB.
__global__ __launch_bounds__(256, 4) void attn_kernel(
    const unsigned short* __restrict__ q,      // [B,NH,S,DH] bf16, scaled log2e/8
    const unsigned short* __restrict__ kperm,  // fragment-tile K
    const unsigned short* __restrict__ vperm,  // fragment-tile V
    const float* __restrict__ eam,             // [B,S] = exp(amask)
    const unsigned long long* __restrict__ bm, // [B,S,S/64] bitmask
    const float* __restrict__ gate,            // [B,NH,S]
    float* __restrict__ out) {                 // [B,S,H]
  __shared__ alignas(16) unsigned short Ks[2][4096];
  __shared__ alignas(16) unsigned short Vs[2][4096];

  const int flat = blockIdx.x;
  const int h = (flat & 7) + 8 * ((flat >> 3) & 1);
  const int b = (flat >> 4) & 1;
  const int qt = flat >> 5;
  const int tid = threadIdx.x, lane = tid & 63, wvi = tid >> 6;
  const int quad = lane >> 4, l16 = lane & 15;
  const int bh = b * NH_ + h;
  const int q0 = qt * 64 + wvi * 16;  // wave's 16 q-rows; this lane's q = q0+l16

  const unsigned short* qrow = q + ((size_t)bh * S_ + q0 + l16) * DH_;
  short8 qf0 = *reinterpret_cast<const short8*>(qrow + quad * 8);
  short8 qf1 = *reinterpret_cast<const short8*>(qrow + 32 + quad * 8);

  floatx4 zf = {0.f, 0.f, 0.f, 0.f};
  float psg = 0.f, psl = 0.f;
  floatx4 accg[4], accl[4];   // Oᵀ tiles: row d = dtile*16+quad*4+r, col q = l16
#pragma unroll
  for (int i = 0; i < 4; i++) { accg[i] = zf; accl[i] = zf; }

  const unsigned short* kp = kperm + (size_t)bh * 131072;
  const unsigned short* vp = vperm + (size_t)bh * 131072;
  const float* eamb = eam + (size_t)b * S_;
  const unsigned long long* bmq = bm + ((size_t)b * S_ + q0 + l16) * (S_ / 64);

  // staging: thread tid copies tile elems [tid*8,+8) and [2048+tid*8,+8)
  // (both global-coalesced; both ds_write_b128 lane-contiguous -> 0 conflicts)
  const int soA = tid * 8, soB = 2048 + tid * 8;
  const unsigned short* kgA = kp + soA;
  const unsigned short* kgB = kp + soB;
  const unsigned short* vgA = vp + soA;
  const unsigned short* vgB = vp + soB;

  // prologue: stage tile 0 into buf0; prefetch tile 1 into regs
  uint4 pk0 = *reinterpret_cast<const uint4*>(kgA);
  uint4 pk1 = *reinterpret_cast<const uint4*>(kgB);
  uint4 pv0 = *reinterpret_cast<const uint4*>(vgA);
  uint4 pv1 = *reinterpret_cast<const uint4*>(vgB);
  *reinterpret_cast<uint4*>(&Ks[0][soA]) = pk0;
  *reinterpret_cast<uint4*>(&Ks[0][soB]) = pk1;
  *reinterpret_cast<uint4*>(&Vs[0][soA]) = pv0;
  *reinterpret_cast<uint4*>(&Vs[0][soB]) = pv1;
  pk0 = *reinterpret_cast<const uint4*>(kgA + 4096);
  pk1 = *reinterpret_cast<const uint4*>(kgB + 4096);
  pv0 = *reinterpret_cast<const uint4*>(vgA + 4096);
  pv1 = *reinterpret_cast<const uint4*>(vgB + 4096);

  for (int kt = 0; kt < S_ / 64; kt++) {
    __syncthreads();  // buf[kt&1] visible; buf[(kt+1)&1] readers (iter kt-1) done
    // ---- stage tile kt+1 from regs (conflict-free b128 writes) ----
    {
      const int bn = (kt + 1) & 1;
      *reinterpret_cast<uint4*>(&Ks[bn][soA]) = pk0;
      *reinterpret_cast<uint4*>(&Ks[bn][soB]) = pk1;
      *reinterpret_cast<uint4*>(&Vs[bn][soA]) = pv0;
      *reinterpret_cast<uint4*>(&Vs[bn][soB]) = pv1;
    }
    // ---- prefetch tile kt+2 into regs (wraps; ~full iter of latency slack) ----
    {
      const int tb = ((kt + 2) & 31) * 4096;
      pk0 = *reinterpret_cast<const uint4*>(kgA + tb);
      pk1 = *reinterpret_cast<const uint4*>(kgB + tb);
      pv0 = *reinterpret_cast<const uint4*>(vgA + tb);
      pv1 = *reinterpret_cast<const uint4*>(vgB + tb);
    }
    const int k0 = kt * 64;
    // ---- per-lane mask bits + eam (independent loads, issued early) ----
    unsigned long long w = bmq[kt];
    float4 ea[4];
#pragma unroll
    for (int t = 0; t < 4; t++)
      ea[t] = *reinterpret_cast<const float4*>(eamb + k0 + t * 16 + quad * 4);

    const unsigned short* Kc = Ks[kt & 1];
    const unsigned short* Vc = Vs[kt & 1];
    // ---- QKᵀ from LDS (lane-order contiguous b128 reads) ----
    floatx4 scT[4];
#pragma unroll
    for (int t = 0; t < 4; t++) {
      const unsigned short* kr = Kc + t * 1024 + lane * 8;
      short8 kf0 = *reinterpret_cast<const short8*>(kr);
      short8 kf1 = *reinterpret_cast<const short8*>(kr + 512);
      scT[t] = __builtin_amdgcn_mfma_f32_16x16x32_bf16(kf0, qf0, zf, 0, 0, 0);
      scT[t] = __builtin_amdgcn_mfma_f32_16x16x32_bf16(kf1, qf1, scT[t], 0, 0, 0);
    }
    // ---- shared-exp dual softmax (exp2; q carries log2e/8) ----
    int pgf[4][2], plf[4][2];
#pragma unroll
    for (int t = 0; t < 4; t++) {
      unsigned m4 = (unsigned)(w >> (t * 16 + quad * 4)) & 0xFu;
      float e0 = __builtin_amdgcn_exp2f(scT[t][0]);
      float e1 = __builtin_amdgcn_exp2f(scT[t][1]);
      float e2 = __builtin_amdgcn_exp2f(scT[t][2]);
      float e3 = __builtin_amdgcn_exp2f(scT[t][3]);
      float g0 = e0 * ea[t].x, g1 = e1 * ea[t].y, g2 = e2 * ea[t].z, g3 = e3 * ea[t].w;
      psg += (g0 + g1) + (g2 + g3);
      float l0 = (m4 & 1u) ? e0 : 0.f;
      float l1 = (m4 & 2u) ? e1 : 0.f;
      float l2 = (m4 & 4u) ? e2 : 0.f;
      float l3 = (m4 & 8u) ? e3 : 0.f;
      psl += (l0 + l1) + (l2 + l3);
      pgf[t][0] = pack2bf(g0, g1); pgf[t][1] = pack2bf(g2, g3);
      plf[t][0] = pack2bf(l0, l1); plf[t][1] = pack2bf(l2, l3);
    }
    // ---- PV from LDS: Oᵀ += Vᵀ·P (lane-order contiguous b64 reads) ----
#pragma unroll
    for (int d = 0; d < 4; d++) {
#pragma unroll
      for (int t = 0; t < 4; t++) {
        short4v vf = *reinterpret_cast<const short4v*>(Vc + d * 1024 + t * 256 + lane * 4);
        short4v pg = *reinterpret_cast<const short4v*>(&pgf[t][0]);
        short4v pl = *reinterpret_cast<const short4v*>(&plf[t][0]);
        accg[d] = __builtin_amdgcn_mfma_f32_16x16x16bf16_1k(vf, pg, accg[d], 0, 0, 0);
        accl[d] = __builtin_amdgcn_mfma_f32_16x16x16bf16_1k(vf, pl, accl[d], 0, 0, 0);
      }
    }
  }

  // ---- epilogue: quad-reduce denominators, gate-combine, float4 stores ----
  float lgf = psg;
  lgf += __shfl_xor(lgf, 16, 64);
  lgf += __shfl_xor(lgf, 32, 64);
  float llf = psl;
  llf += __shfl_xor(llf, 16, 64);
  llf += __shfl_xor(llf, 32, 64);
  const int s = q0 + l16;
  const float g = gate[(size_t)bh * S_ + s];
  const float cg = (1.f - g) / lgf, cl = g / llf;
  float* orow = out + ((size_t)b * S_ + s) * H_ + h * DH_ + quad * 4;
#pragma unroll
  for (int d = 0; d < 4; d++) {
    float4 o;
    o.x = cl * accl[d][0] + cg * accg[d][0];
    o.y = cl * accl[d][1] + cg * accg[d][1];
    o.z = cl * accl[d][2] + cg * accg[d][2];
    o.w = cl * accl[d][3] + cg * accg[d][3];
    *reinterpret_cast<float4*>(orow + d * 16) = o;
  }
}

extern "C" void kernel_launch(void* const* d_in, const int* in_sizes, int n_in,
                              void* d_out, int out_size, void* d_ws, size_t ws_size,
                              hipStream_t stream) {
  (void)in_sizes; (void)n_in; (void)out_size; (void)ws_size;
  const float* hs = (const float*)d_in[0];
  const float* am = (const float*)d_in[1];
  const int* lm = (const int*)d_in[2];
  const float* gate = (const float*)d_in[3];
  const float* Wq = (const float*)d_in[4];
  const float* bq = (const float*)d_in[5];
  const float* Wk = (const float*)d_in[6];
  const float* bk = (const float*)d_in[7];
  const float* Wv = (const float*)d_in[8];
  const float* bv = (const float*)d_in[9];
  float* out = (float*)d_out;

  unsigned short* ws = (unsigned short*)d_ws;
  unsigned short* hbf = ws;                  // 4,194,304 elems
  unsigned short* wqb = hbf + 4194304;       // 1,048,576
  unsigned short* wkb = wqb + 1048576;
  unsigned short* wvb = wkb + 1048576;
  unsigned short* qb = wvb + 1048576;        // 4,194,304
  unsigned short* kb = qb + 4194304;
  unsigned short* vtb = kb + 4194304;
  unsigned long long* bmp = (unsigned long long*)(vtb + 4194304);  // 1 MB
  float* eamp = (float*)(bmp + 131072);      // 4096 floats

  cvt_bf16<<<4096, 256, 0, stream>>>(hs, hbf, 4194304);
  cvt_bf16<<<1024, 256, 0, stream>>>(Wq, wqb, 1048576);
  cvt_bf16<<<1024, 256, 0, stream>>>(Wk, wkb, 1048576);
  cvt_bf16<<<1024, 256, 0, stream>>>(Wv, wvb, 1048576);
  build_bitmask<<<32768, 256, 0, stream>>>(lm, bmp);
  build_eam<<<16, 256, 0, stream>>>(am, eamp);
  gemm_qkv<<<dim3(32, 8, 3), 256, 0, stream>>>(hbf, wqb, wkb, wvb, bq, bk, bv, qb, kb, vtb);
  attn_kernel<<<dim3(1024), 256, 0, stream>>>(qb, kb, vtb, eamp, bmp, gate, out);
}

// Round 10
// 266.846 us; speedup vs baseline: 1.2479x; 1.0487x over previous
//
#include <hip/hip_runtime.h>
#include <cstdint>
#include <cstddef>

typedef short short8 __attribute__((ext_vector_type(8)));
typedef short short4v __attribute__((ext_vector_type(4)));
typedef float floatx4 __attribute__((ext_vector_type(4)));
typedef unsigned short ushort4v __attribute__((ext_vector_type(4)));

constexpr int B_ = 2, S_ = 2048, H_ = 1024, NH_ = 16, DH_ = 64;
constexpr int K_ = H_;        // 1024

__device__ __forceinline__ unsigned short f2bf(float f) {
  unsigned u = __float_as_uint(f);
  u += 0x7fffu + ((u >> 16) & 1u);   // RNE
  return (unsigned short)(u >> 16);
}

// pack two floats to bf16x2 (round-half-up; bias cancels in p/sum(p))
__device__ __forceinline__ unsigned pack2bf(float a, float b) {
  unsigned ua = (__float_as_uint(a) + 0x8000u) >> 16;
  unsigned ub = (__float_as_uint(b) + 0x8000u) & 0xffff0000u;
  return ua | ub;
}

// ---------------- fused prep: cvt hs / cvt W x3 / bitmask / eam ----------------
// One launch instead of six (each extra dispatch costs ~5-13 us of gap).
// Block ranges: [0,4096) hs cvt; [4096,7168) W cvt; [7168,39936) bitmask; [39936,39952) eam.
__global__ __launch_bounds__(256) void prep_kernel(
    const float* __restrict__ hs, unsigned short* __restrict__ hbf,
    const float* __restrict__ Wq, const float* __restrict__ Wk, const float* __restrict__ Wv,
    unsigned short* __restrict__ wqb, unsigned short* __restrict__ wkb,
    unsigned short* __restrict__ wvb,
    const int* __restrict__ lm, unsigned long long* __restrict__ bm,
    const float* __restrict__ am, float* __restrict__ ea) {
  const int bid = blockIdx.x, tid = threadIdx.x;
  if (bid < 7168) {
    const float* in;
    unsigned short* out;
    int off;
    if (bid < 4096) { in = hs; out = hbf; off = bid; }
    else {
      int wsel = (bid - 4096) >> 10;
      in = (wsel == 0) ? Wq : (wsel == 1) ? Wk : Wv;
      out = (wsel == 0) ? wqb : (wsel == 1) ? wkb : wvb;
      off = (bid - 4096) & 1023;
    }
    int i = (off * 256 + tid) * 4;
    float4 v = *reinterpret_cast<const float4*>(in + i);
    ushort4v o;
    o.x = f2bf(v.x); o.y = f2bf(v.y); o.z = f2bf(v.z); o.w = f2bf(v.w);
    *reinterpret_cast<ushort4v*>(out + i) = o;
  } else if (bid < 39936) {
    int word = (bid - 7168) * 4 + (tid >> 6);
    int lane = tid & 63;
    unsigned long long bits = __ballot(lm[(size_t)word * 64 + lane] != 0);
    if (lane == 0) bm[word] = bits;
  } else {
    int i = (bid - 39936) * 256 + tid;
    ea[i] = __expf(am[i]);
  }
}

// ---------------- async global->LDS 16B ----------------
typedef __attribute__((address_space(1))) const void gvoid;
typedef __attribute__((address_space(3))) void lvoid;
__device__ __forceinline__ void async16(const unsigned short* gp, unsigned short* lp) {
  __builtin_amdgcn_global_load_lds((gvoid*)gp, (lvoid*)lp, 16, 0, 0);
}

// ---------------- QKV projection GEMM ----------------
// z=0 -> q scaled by 0.125*log2(e), layout [B,NH,S,DH]   (TRANSPOSED C: see below)
// z=1 -> K in FRAGMENT-TILE order (TRANSPOSED C)
// z=2 -> V in FRAGMENT-TILE order (normal C)
// Operand swap for z<2: mfma(bfr, af, ..) gives C[row=W-row(d), col=hidden-row(s)],
// so each lane's 4 C-regs hold 4 CONSECUTIVE dh -> vectorized/coalesced stores
// (z=1 becomes fully-coalesced 1KB-per-wave 8B stores; z=0 8B instead of 4x2B).
__global__ __launch_bounds__(256) void gemm_qkv(
    const unsigned short* __restrict__ A,
    const unsigned short* __restrict__ Wq, const unsigned short* __restrict__ Wk,
    const unsigned short* __restrict__ Wv,
    const float* __restrict__ bq, const float* __restrict__ bk, const float* __restrict__ bv,
    unsigned short* __restrict__ qo, unsigned short* __restrict__ ko,
    unsigned short* __restrict__ vo) {
  __shared__ alignas(16) unsigned short As[128 * 32];
  __shared__ alignas(16) unsigned short Bs[128 * 32];
  const int z = blockIdx.z;
  const unsigned short* W = (z == 0) ? Wq : (z == 1) ? Wk : Wv;
  const float* bias = (z == 0) ? bq : (z == 1) ? bk : bv;

  const int m0 = blockIdx.x * 128, n0 = blockIdx.y * 128;
  const int tid = threadIdx.x, lane = tid & 63, wvi = tid >> 6;
  const int wr = wvi >> 1, wc = wvi & 1, quad = lane >> 4, l16 = lane & 15;

  floatx4 zf = {0.f, 0.f, 0.f, 0.f};
  floatx4 acc[4][4];
  for (int i = 0; i < 4; i++)
    for (int j = 0; j < 4; j++) acc[i][j] = zf;

  for (int kk = 0; kk < K_; kk += 32) {
#pragma unroll
    for (int i = 0; i < 2; i++) {
      int cb = wvi * 128 + i * 64;   // wave-uniform chunk base (lds dest = base + lane*16B)
      int c = cb + lane;
      int row = c >> 2, kc = c & 3;
      async16(A + (size_t)(m0 + row) * K_ + kk + kc * 8, As + cb * 8);
      async16(W + (size_t)(n0 + row) * K_ + kk + kc * 8, Bs + cb * 8);
    }
    __syncthreads();
    short8 af[4], bfr[4];
#pragma unroll
    for (int mf = 0; mf < 4; mf++)
      af[mf] = *reinterpret_cast<const short8*>(&As[(wr * 64 + mf * 16 + l16) * 32 + quad * 8]);
#pragma unroll
    for (int nf = 0; nf < 4; nf++)
      bfr[nf] = *reinterpret_cast<const short8*>(&Bs[(wc * 64 + nf * 16 + l16) * 32 + quad * 8]);
    if (z == 2) {
#pragma unroll
      for (int mf = 0; mf < 4; mf++)
#pragma unroll
        for (int nf = 0; nf < 4; nf++)
          acc[mf][nf] = __builtin_amdgcn_mfma_f32_16x16x32_bf16(af[mf], bfr[nf], acc[mf][nf], 0, 0, 0);
    } else {
#pragma unroll
      for (int mf = 0; mf < 4; mf++)
#pragma unroll
        for (int nf = 0; nf < 4; nf++)
          acc[mf][nf] = __builtin_amdgcn_mfma_f32_16x16x32_bf16(bfr[nf], af[mf], acc[mf][nf], 0, 0, 0);
    }
    __syncthreads();
  }

  if (z == 2) {
    // normal C: row = key = m-base + quad*4+r, col = d-row = n-base + l16
#pragma unroll
    for (int mf = 0; mf < 4; mf++) {
      int mbase = m0 + wr * 64 + mf * 16 + quad * 4;
      int b = mbase >> 11, s0 = mbase & 2047;
#pragma unroll
      for (int nf = 0; nf < 4; nf++) {
        int n = n0 + wc * 64 + nf * 16 + l16;
        int h = n >> 6, d = n & 63;
        int bh = b * NH_ + h;
        float bvv = bias[n];
        floatx4 c = acc[mf][nf];
        size_t base = (size_t)bh * 131072 + (s0 >> 6) * 4096 + (d >> 4) * 1024 +
                      ((s0 >> 4) & 3) * 256 + ((s0 >> 2) & 3) * 64 + (d & 15) * 4;
        ushort4v p;
        p.x = f2bf(c[0] + bvv); p.y = f2bf(c[1] + bvv);
        p.z = f2bf(c[2] + bvv); p.w = f2bf(c[3] + bvv);
        *reinterpret_cast<ushort4v*>(&vo[base]) = p;
      }
    }
  } else {
    // transposed C: row = d-row = n-base + quad*4+r, col = key/seq = m-base + l16
#pragma unroll
    for (int mf = 0; mf < 4; mf++) {
      int s = m0 + wr * 64 + mf * 16 + l16;   // seq index
      int b = s >> 11;
      int sq = s & 2047;
#pragma unroll
      for (int nf = 0; nf < 4; nf++) {
        int nn = n0 + wc * 64 + nf * 16 + quad * 4;  // d' base, 4-aligned
        int h = nn >> 6, dh = nn & 63;
        int bh = b * NH_ + h;
        float4 b4 = *reinterpret_cast<const float4*>(bias + nn);
        floatx4 c = acc[mf][nf];
        if (z == 0) {
          ushort4v p;
          p.x = f2bf((c[0] + b4.x) * 0.18033688011112042f);  // 0.125*log2(e)
          p.y = f2bf((c[1] + b4.y) * 0.18033688011112042f);
          p.z = f2bf((c[2] + b4.z) * 0.18033688011112042f);
          p.w = f2bf((c[3] + b4.w) * 0.18033688011112042f);
          *reinterpret_cast<ushort4v*>(&qo[((size_t)bh * S_ + sq) * DH_ + dh]) = p;
        } else {
          size_t base = (size_t)bh * 131072 + (sq >> 6) * 4096 + ((sq >> 4) & 3) * 1024 +
                        (dh >> 5) * 512 + ((dh >> 3) & 3) * 128 + (sq & 15) * 8 + (dh & 7);
          ushort4v p;
          p.x = f2bf(c[0] + b4.x); p.y = f2bf(c[1] + b4.y);
          p.z = f2bf(c[2] + b4.z); p.w = f2bf(c[3] + b4.w);
          *reinterpret_cast<ushort4v*>(&ko[base]) = p;
        }
      }
    }
  }
}

// ------- dual-softmax flash attention (r9 structure, verified: 0 conflicts) -------
__global__ __launch_bounds__(256, 4) void attn_kernel(
    const unsigned short* __restrict__ q,      // [B,NH,S,DH] bf16, scaled log2e/8
    const unsigned short* __restrict__ kperm,  // fragment-tile K
    const unsigned short* __restrict__ vperm,  // fragment-tile V
    const float* __restrict__ eam,             // [B,S] = exp(amask)
    const unsigned long long* __restrict__ bm, // [B,S,S/64] bitmask
    const float* __restrict__ gate,            // [B,NH,S]
    float* __restrict__ out) {                 // [B,S,H]
  __shared__ alignas(16) unsigned short Ks[2][4096];
  __shared__ alignas(16) unsigned short Vs[2][4096];

  const int flat = blockIdx.x;
  const int h = (flat & 7) + 8 * ((flat >> 3) & 1);
  const int b = (flat >> 4) & 1;
  const int qt = flat >> 5;
  const int tid = threadIdx.x, lane = tid & 63, wvi = tid >> 6;
  const int quad = lane >> 4, l16 = lane & 15;
  const int bh = b * NH_ + h;
  const int q0 = qt * 64 + wvi * 16;  // wave's 16 q-rows; this lane's q = q0+l16

  const unsigned short* qrow = q + ((size_t)bh * S_ + q0 + l16) * DH_;
  short8 qf0 = *reinterpret_cast<const short8*>(qrow + quad * 8);
  short8 qf1 = *reinterpret_cast<const short8*>(qrow + 32 + quad * 8);

  floatx4 zf = {0.f, 0.f, 0.f, 0.f};
  float psg = 0.f, psl = 0.f;
  floatx4 accg[4], accl[4];   // Oᵀ tiles: row d = dtile*16+quad*4+r, col q = l16
#pragma unroll
  for (int i = 0; i < 4; i++) { accg[i] = zf; accl[i] = zf; }

  const unsigned short* kp = kperm + (size_t)bh * 131072;
  const unsigned short* vp = vperm + (size_t)bh * 131072;
  const float* eamb = eam + (size_t)b * S_;
  const unsigned long long* bmq = bm + ((size_t)b * S_ + q0 + l16) * (S_ / 64);

  // staging: thread tid copies tile elems [tid*8,+8) and [2048+tid*8,+8)
  const int soA = tid * 8, soB = 2048 + tid * 8;
  const unsigned short* kgA = kp + soA;
  const unsigned short* kgB = kp + soB;
  const unsigned short* vgA = vp + soA;
  const unsigned short* vgB = vp + soB;

  // prologue: stage tile 0 into buf0; prefetch tile 1 into regs
  uint4 pk0 = *reinterpret_cast<const uint4*>(kgA);
  uint4 pk1 = *reinterpret_cast<const uint4*>(kgB);
  uint4 pv0 = *reinterpret_cast<const uint4*>(vgA);
  uint4 pv1 = *reinterpret_cast<const uint4*>(vgB);
  *reinterpret_cast<uint4*>(&Ks[0][soA]) = pk0;
  *reinterpret_cast<uint4*>(&Ks[0][soB]) = pk1;
  *reinterpret_cast<uint4*>(&Vs[0][soA]) = pv0;
  *reinterpret_cast<uint4*>(&Vs[0][soB]) = pv1;
  pk0 = *reinterpret_cast<const uint4*>(kgA + 4096);
  pk1 = *reinterpret_cast<const uint4*>(kgB + 4096);
  pv0 = *reinterpret_cast<const uint4*>(vgA + 4096);
  pv1 = *reinterpret_cast<const uint4*>(vgB + 4096);

  for (int kt = 0; kt < S_ / 64; kt++) {
    __syncthreads();  // buf[kt&1] visible; buf[(kt+1)&1] readers (iter kt-1) done
    // ---- stage tile kt+1 from regs (conflict-free b128 writes) ----
    {
      const int bn = (kt + 1) & 1;
      *reinterpret_cast<uint4*>(&Ks[bn][soA]) = pk0;
      *reinterpret_cast<uint4*>(&Ks[bn][soB]) = pk1;
      *reinterpret_cast<uint4*>(&Vs[bn][soA]) = pv0;
      *reinterpret_cast<uint4*>(&Vs[bn][soB]) = pv1;
    }
    // ---- prefetch tile kt+2 into regs (wraps; ~full iter of latency slack) ----
    {
      const int tb = ((kt + 2) & 31) * 4096;
      pk0 = *reinterpret_cast<const uint4*>(kgA + tb);
      pk1 = *reinterpret_cast<const uint4*>(kgB + tb);
      pv0 = *reinterpret_cast<const uint4*>(vgA + tb);
      pv1 = *reinterpret_cast<const uint4*>(vgB + tb);
    }
    const int k0 = kt * 64;
    // ---- per-lane mask bits + eam (independent loads, issued early) ----
    unsigned long long w = bmq[kt];
    float4 ea[4];
#pragma unroll
    for (int t = 0; t < 4; t++)
      ea[t] = *reinterpret_cast<const float4*>(eamb + k0 + t * 16 + quad * 4);

    const unsigned short* Kc = Ks[kt & 1];
    const unsigned short* Vc = Vs[kt & 1];
    // ---- QKᵀ from LDS (lane-order contiguous b128 reads) ----
    floatx4 scT[4];
#pragma unroll
    for (int t = 0; t < 4; t++) {
      const unsigned short* kr = Kc + t * 1024 + lane * 8;
      short8 kf0 = *reinterpret_cast<const short8*>(kr);
      short8 kf1 = *reinterpret_cast<const short8*>(kr + 512);
      scT[t] = __builtin_amdgcn_mfma_f32_16x16x32_bf16(kf0, qf0, zf, 0, 0, 0);
      scT[t] = __builtin_amdgcn_mfma_f32_16x16x32_bf16(kf1, qf1, scT[t], 0, 0, 0);
    }
    // ---- shared-exp dual softmax (exp2; q carries log2e/8) ----
    int pgf[4][2], plf[4][2];
#pragma unroll
    for (int t = 0; t < 4; t++) {
      unsigned m4 = (unsigned)(w >> (t * 16 + quad * 4)) & 0xFu;
      float e0 = __builtin_amdgcn_exp2f(scT[t][0]);
      float e1 = __builtin_amdgcn_exp2f(scT[t][1]);
      float e2 = __builtin_amdgcn_exp2f(scT[t][2]);
      float e3 = __builtin_amdgcn_exp2f(scT[t][3]);
      float g0 = e0 * ea[t].x, g1 = e1 * ea[t].y, g2 = e2 * ea[t].z, g3 = e3 * ea[t].w;
      psg += (g0 + g1) + (g2 + g3);
      float l0 = (m4 & 1u) ? e0 : 0.f;
      float l1 = (m4 & 2u) ? e1 : 0.f;
      float l2 = (m4 & 4u) ? e2 : 0.f;
      float l3 = (m4 & 8u) ? e3 : 0.f;
      psl += (l0 + l1) + (l2 + l3);
      pgf[t][0] = pack2bf(g0, g1); pgf[t][1] = pack2bf(g2, g3);
      plf[t][0] = pack2bf(l0, l1); plf[t][1] = pack2bf(l2, l3);
    }
    // ---- PV from LDS: Oᵀ += Vᵀ·P (lane-order contiguous b64 reads) ----
#pragma unroll
    for (int d = 0; d < 4; d++) {
#pragma unroll
      for (int t = 0; t < 4; t++) {
        short4v vf = *reinterpret_cast<const short4v*>(Vc + d * 1024 + t * 256 + lane * 4);
        short4v pg = *reinterpret_cast<const short4v*>(&pgf[t][0]);
        short4v pl = *reinterpret_cast<const short4v*>(&plf[t][0]);
        accg[d] = __builtin_amdgcn_mfma_f32_16x16x16bf16_1k(vf, pg, accg[d], 0, 0, 0);
        accl[d] = __builtin_amdgcn_mfma_f32_16x16x16bf16_1k(vf, pl, accl[d], 0, 0, 0);
      }
    }
  }

  // ---- epilogue: quad-reduce denominators, gate-combine, float4 stores ----
  float lgf = psg;
  lgf += __shfl_xor(lgf, 16, 64);
  lgf += __shfl_xor(lgf, 32, 64);
  float llf = psl;
  llf += __shfl_xor(llf, 16, 64);
  llf += __shfl_xor(llf, 32, 64);
  const int s = q0 + l16;
  const float g = gate[(size_t)bh * S_ + s];
  const float cg = (1.f - g) / lgf, cl = g / llf;
  float* orow = out + ((size_t)b * S_ + s) * H_ + h * DH_ + quad * 4;
#pragma unroll
  for (int d = 0; d < 4; d++) {
    float4 o;
    o.x = cl * accl[d][0] + cg * accg[d][0];
    o.y = cl * accl[d][1] + cg * accg[d][1];
    o.z = cl * accl[d][2] + cg * accg[d][2];
    o.w = cl * accl[d][3] + cg * accg[d][3];
    *reinterpret_cast<float4*>(orow + d * 16) = o;
  }
}

extern "C" void kernel_launch(void* const* d_in, const int* in_sizes, int n_in,
                              void* d_out, int out_size, void* d_ws, size_t ws_size,
                              hipStream_t stream) {
  (void)in_sizes; (void)n_in; (void)out_size; (void)ws_size;
  const float* hs = (const float*)d_in[0];
  const float* am = (const float*)d_in[1];
  const int* lm = (const int*)d_in[2];
  const float* gate = (const float*)d_in[3];
  const float* Wq = (const float*)d_in[4];
  const float* bq = (const float*)d_in[5];
  const float* Wk = (const float*)d_in[6];
  const float* bk = (const float*)d_in[7];
  const float* Wv = (const float*)d_in[8];
  const float* bv = (const float*)d_in[9];
  float* out = (float*)d_out;

  unsigned short* ws = (unsigned short*)d_ws;
  unsigned short* hbf = ws;                  // 4,194,304 elems
  unsigned short* wqb = hbf + 4194304;       // 1,048,576
  unsigned short* wkb = wqb + 1048576;
  unsigned short* wvb = wkb + 1048576;
  unsigned short* qb = wvb + 1048576;        // 4,194,304
  unsigned short* kb = qb + 4194304;
  unsigned short* vtb = kb + 4194304;
  unsigned long long* bmp = (unsigned long long*)(vtb + 4194304);  // 1 MB
  float* eamp = (float*)(bmp + 131072);      // 4096 floats

  prep_kernel<<<39952, 256, 0, stream>>>(hs, hbf, Wq, Wk, Wv, wqb, wkb, wvb, lm, bmp, am, eamp);
  gemm_qkv<<<dim3(32, 8, 3), 256, 0, stream>>>(hbf, wqb, wkb, wvb, bq, bk, bv, qb, kb, vtb);
  attn_kernel<<<dim3(1024), 256, 0, stream>>>(qb, kb, vtb, eamp, bmp, gate, out);
}